// Round 1
// baseline (380.039 us; speedup 1.0000x reference)
//
#include <hip/hip_runtime.h>

// SecConv2d over Z_{2^32} (low 32 bits of the reference's Z_{2^64} result).
// x: (32,64,56,56) int32 in [0,65536); w: (64,64,3,3); bias: (64,)
// out: (32,64,56,56) int32 = wrap(conv + bias).
//
// Block: 448 threads = 8 rows x 56 cols of one batch's output tile.
// Grid:  (7 row-groups, 4 k-groups of 16 output channels, 32 batches).
// Input staged in LDS in chunks of 8 input channels; 16 accumulators per
// thread give independent VALU chains; weights are wave-uniform -> s_load.

#define CC 8           // input channels per LDS chunk
#define KG 16          // output channels per block
#define TH 8           // output rows per block
#define TW 56          // output cols per block (full width)
#define TROWS (TH + 2) // 10
#define TCOLS (TW + 2) // 58
#define NTHREADS (TH * TW) // 448

__global__ __launch_bounds__(NTHREADS) void secconv_kernel(
    const int* __restrict__ x,
    const int* __restrict__ w,
    const int* __restrict__ bias,
    int* __restrict__ out)
{
    __shared__ int tile[CC][TROWS][TCOLS];

    const int tid = threadIdx.x;
    const int row = tid / TW;   // 0..7
    const int col = tid % TW;   // 0..55

    const int rg = blockIdx.x;  // 0..6  row group
    const int kg = blockIdx.y;  // 0..3  output-channel group
    const int n  = blockIdx.z;  // 0..31 batch

    const int oh0 = rg * TH;
    const int k0  = kg * KG;

    const int HW = 56 * 56;
    const long xbase = (long)n * 64 * HW;

    unsigned acc[KG];
#pragma unroll
    for (int j = 0; j < KG; ++j)
        acc[j] = (unsigned)bias[k0 + j];

    for (int cc = 0; cc < 64; cc += CC) {
        __syncthreads();
        // ---- stage CC channels of the (TROWS x TCOLS) input halo tile ----
        for (int idx = tid; idx < CC * TROWS * TCOLS; idx += NTHREADS) {
            int c   = idx / (TROWS * TCOLS);
            int rem = idx - c * (TROWS * TCOLS);
            int r   = rem / TCOLS;
            int cl  = rem - r * TCOLS;
            int ih  = oh0 - 1 + r;
            int iw  = cl - 1;
            int v = 0;
            if ((unsigned)ih < 56u && (unsigned)iw < 56u)
                v = x[xbase + (long)(cc + c) * HW + ih * 56 + iw];
            ((int*)tile)[idx] = v;
        }
        __syncthreads();

        // ---- accumulate this chunk ----
#pragma unroll
        for (int c = 0; c < CC; ++c) {
            unsigned iv[9];
#pragma unroll
            for (int r = 0; r < 3; ++r)
#pragma unroll
                for (int s = 0; s < 3; ++s)
                    // mask to 24 bits: values are < 2^16, enables mul24/mad24
                    iv[r * 3 + s] = (unsigned)tile[c][row + r][col + s] & 0xFFFFFFu;

#pragma unroll
            for (int j = 0; j < KG; ++j) {
                const int* wp = w + ((long)(k0 + j) * 64 + (cc + c)) * 9;
#pragma unroll
                for (int t = 0; t < 9; ++t) {
                    unsigned wv = (unsigned)wp[t] & 0xFFFFFFu;
                    acc[j] += wv * iv[t];   // -> v_mad_u32_u24
                }
            }
        }
    }

    // ---- epilogue: coalesced stores, 16 channels per thread ----
    const long obase = ((long)n * 64 + k0) * HW + (oh0 + row) * 56 + col;
#pragma unroll
    for (int j = 0; j < KG; ++j)
        out[obase + (long)j * HW] = (int)acc[j];
}

extern "C" void kernel_launch(void* const* d_in, const int* in_sizes, int n_in,
                              void* d_out, int out_size, void* d_ws, size_t ws_size,
                              hipStream_t stream)
{
    const int* x    = (const int*)d_in[0];
    const int* w    = (const int*)d_in[1];
    const int* bias = (const int*)d_in[2];
    int* out        = (int*)d_out;

    dim3 grid(7, 4, 32);   // row-groups, k-groups, batches
    dim3 block(NTHREADS);
    secconv_kernel<<<grid, block, 0, stream>>>(x, w, bias, out);
}

// Round 3
// 208.099 us; speedup vs baseline: 1.8262x; 1.8262x over previous
//
#include <hip/hip_runtime.h>

// SecConv2d over Z_{2^32} (low 32 bits == mod-2^64 result truncated to i32).
// x:(32,64,56,56) i32 in [0,65536), w:(64,64,3,3), bias:(64,).
//
// Channel-pair u16 packing + v_dot2_u32_u16: 2 MACs/instr, wrap mod 2^32.
// Weights prepacked (u16 pairs) into a __device__ global; compute reads them
// with wave-uniform indices -> scalar loads (off the LDS pipe).
// Block = 224 thr = 28 rows x 8 col-groups(7 cols), KG=8 out-channels.
// LDS: 4 packed planes (8 input channels) of 30x59 words = 28.3 KB.
// Grid = 512 (2 rowhalves x 8 kgroups x 32 batches), XCD-swizzled by batch.

#define HW 3136
#define HALOW 59
#define PLW (30 * 59)   // 1770 words per packed plane
#define NTH 224
#define KG 8

__device__ unsigned g_wpack[32 * 64 * 9];   // [cpair][k][t], lo=even c, hi=odd c

typedef unsigned short u16x2 __attribute__((ext_vector_type(2)));

static __device__ __forceinline__ unsigned dot2(unsigned a, unsigned b, unsigned c) {
#if __has_builtin(__builtin_amdgcn_udot2)
    return __builtin_amdgcn_udot2(__builtin_bit_cast(u16x2, a),
                                  __builtin_bit_cast(u16x2, b), c, false);
#else
    c += __umul24(a & 0xFFFFu, b & 0xFFFFu);
    c += __umul24(a >> 16, b >> 16);
    return c;
#endif
}

__global__ __launch_bounds__(256) void prepack(const int* __restrict__ w) {
    int i = blockIdx.x * 256 + threadIdx.x;          // [cp][k][t] flat, 18432
    if (i >= 32 * 64 * 9) return;
    int t  = i % 9;
    int k  = (i / 9) % 64;
    int cp = i / 576;
    unsigned lo = (unsigned)w[(k * 64 + 2 * cp    ) * 9 + t] & 0xFFFFu;
    unsigned hi = (unsigned)w[(k * 64 + 2 * cp + 1) * 9 + t] & 0xFFFFu;
    g_wpack[i] = lo | (hi << 16);
}

__global__ __launch_bounds__(NTH, 2) void secconv(
    const int* __restrict__ x, const int* __restrict__ bias,
    int* __restrict__ out)
{
    __shared__ unsigned sx[4 * PLW];    // 28.3 KB

    const int tid = threadIdx.x;
    // decode: blk bits -> xcd(3) | rh(1) kg(3) nhi(2); all 16 blocks of a
    // batch land on one XCD for L2 reuse of x.
    const int blk = blockIdx.x;
    const int q   = blk >> 3;
    const int rh  = q & 1;
    const int kg  = (q >> 1) & 7;
    const int n   = (blk & 7) | ((q >> 4) << 3);
    const int k0  = kg * KG;
    const int oh0 = rh * 28;

    const int trow = tid >> 3;          // 0..27 output row (within half)
    const int tc7  = (tid & 7) * 7;     // first of 7 output cols

    // staging slots: 30x58 halo cells at stride-59, 8 slots/thread
    int goff[8], loff[8]; unsigned zm[8];
#pragma unroll
    for (int s = 0; s < 8; ++s) {
        int idx = tid + s * NTH;        // 0..1791; used < 1740
        int r   = idx / 58;
        int cl  = idx - r * 58;
        int ih  = oh0 - 1 + r, iw = cl - 1;
        bool ok = ((unsigned)ih < 56u) && ((unsigned)iw < 56u) && (idx < 1740);
        goff[s] = ok ? (ih * 56 + iw) : 0;
        zm[s]   = ok ? 0xFFFFFFFFu : 0u;
        // OOB lanes write 0 to cell 0 (a halo corner whose value is 0) - safe
        loff[s] = (idx < 1740) ? (r * HALOW + cl) : 0;
    }
    const long xb = (long)n * 64 * HW;

    unsigned acc[KG][7];
#pragma unroll
    for (int j = 0; j < KG; ++j) {
        unsigned b = (unsigned)bias[k0 + j];
#pragma unroll
        for (int p = 0; p < 7; ++p) acc[j][p] = b;
    }

    for (int cp0 = 0; cp0 < 32; cp0 += 4) {     // 8 chunks x 4 channel-pairs
        __syncthreads();
#pragma unroll
        for (int pl = 0; pl < 4; ++pl) {
            const int* xlo = x + xb + (long)(2 * (cp0 + pl)) * HW;
            const int* xhi = xlo + HW;
#pragma unroll
            for (int s = 0; s < 8; ++s) {
                unsigned lo = (unsigned)xlo[goff[s]];
                unsigned hi = (unsigned)xhi[goff[s]];
                sx[pl * PLW + loff[s]] = (lo | (hi << 16)) & zm[s];
            }
        }
        __syncthreads();

#pragma unroll
        for (int pl = 0; pl < 4; ++pl) {
            unsigned win[27];
            const unsigned* tb = sx + pl * PLW + trow * HALOW + tc7;
#pragma unroll
            for (int r = 0; r < 3; ++r)
#pragma unroll
                for (int s2 = 0; s2 < 9; ++s2)
                    win[r * 9 + s2] = tb[r * HALOW + s2];

            const unsigned* wp = g_wpack + ((cp0 + pl) * 64 + k0) * 9;
#pragma unroll
            for (int j = 0; j < KG; ++j) {
                unsigned wv[9];
#pragma unroll
                for (int t = 0; t < 9; ++t) wv[t] = wp[j * 9 + t];
#pragma unroll
                for (int t = 0; t < 9; ++t) {
                    const int r = t / 3, s2 = t - (t / 3) * 3;
#pragma unroll
                    for (int p = 0; p < 7; ++p)
                        acc[j][p] = dot2(win[r * 9 + p + s2], wv[t], acc[j][p]);
                }
            }
        }
    }

    const long ob = ((long)n * 64 + k0) * HW + (long)(oh0 + trow) * 56 + tc7;
#pragma unroll
    for (int j = 0; j < KG; ++j)
#pragma unroll
        for (int p = 0; p < 7; ++p)
            out[ob + (long)j * HW + p] = (int)acc[j][p];
}

extern "C" void kernel_launch(void* const* d_in, const int* in_sizes, int n_in,
                              void* d_out, int out_size, void* d_ws, size_t ws_size,
                              hipStream_t stream)
{
    const int* x    = (const int*)d_in[0];
    const int* w    = (const int*)d_in[1];
    const int* bias = (const int*)d_in[2];
    int* out        = (int*)d_out;

    prepack<<<dim3(72), dim3(256), 0, stream>>>(w);           // 72*256 = 18432
    secconv<<<dim3(512), dim3(NTH), 0, stream>>>(x, bias, out);
}

// Round 4
// 179.296 us; speedup vs baseline: 2.1196x; 1.1606x over previous
//
#include <hip/hip_runtime.h>

// SecConv2d over Z_{2^32} (low 32 bits of the mod-2^64 reference).
// x:(32,64,56,56) i32 in [0,65536), w:(64,64,3,3), bias:(64,).
//
// Stage 1: packx  — x channel pairs -> g_xpack[n][cp][hw] u32 (lo|hi<<16).
// Stage 2: packw  — w channel pairs -> g_wpack[cp][k][9].
// Stage 3: secconv — v_dot2_u32_u16 (2 MACs/instr, exact mod 2^32).
//   Block = 224 thr = 28 output rows x 8 col-groups(7), KG=4 out-channels,
//   half-image (28 rows). Grid = 1024 (2 rh x 16 kg x 32 n), 4 blocks/CU
//   -> 14 waves/CU (~44% occ). LDS: 4 planes of 30x60 u32 = 28.8 KB.
//   Halo borders are constant zero: pre-zeroed once, staging is maskless
//   dwordx2 -> ds_write_b64 pairs.

#define HW 3136
#define NTH 224
#define KG 4
#define LDSW 60
#define PLW (30 * LDSW)   // 1800 words/plane

__device__ __align__(16) unsigned g_xpack[32 * 32 * HW]; // 12.8 MB
__device__ unsigned g_wpack[32 * 64 * 9];                // [cp][k][t]

typedef unsigned short u16x2 __attribute__((ext_vector_type(2)));

static __device__ __forceinline__ unsigned dot2(unsigned a, unsigned b, unsigned c) {
#if __has_builtin(__builtin_amdgcn_udot2)
    return __builtin_amdgcn_udot2(__builtin_bit_cast(u16x2, a),
                                  __builtin_bit_cast(u16x2, b), c, false);
#else
    c += __umul24(a & 0xFFFFu, b & 0xFFFFu);
    c += __umul24(a >> 16, b >> 16);
    return c;
#endif
}

__global__ __launch_bounds__(256) void packx(const int* __restrict__ x) {
    int i = blockIdx.x * 256 + threadIdx.x;      // quad index, 32*32*784
    int p4 = i % 784;
    int cp = (i / 784) % 32;
    int n  = i / (784 * 32);
    const int4* lo = (const int4*)(x + ((long)(n * 64 + 2 * cp)) * HW) + p4;
    const int4* hi = lo + (HW / 4);
    int4 a = *lo;
    int4 b = *hi;
    uint4 o;
    o.x = (unsigned)a.x | ((unsigned)b.x << 16);
    o.y = (unsigned)a.y | ((unsigned)b.y << 16);
    o.z = (unsigned)a.z | ((unsigned)b.z << 16);
    o.w = (unsigned)a.w | ((unsigned)b.w << 16);
    ((uint4*)g_xpack)[i] = o;
}

__global__ __launch_bounds__(256) void packw(const int* __restrict__ w) {
    int i = blockIdx.x * 256 + threadIdx.x;      // [cp][k][t] flat, 18432
    if (i >= 32 * 64 * 9) return;
    int t  = i % 9;
    int k  = (i / 9) % 64;
    int cp = i / 576;
    unsigned lo = (unsigned)w[(k * 64 + 2 * cp    ) * 9 + t] & 0xFFFFu;
    unsigned hi = (unsigned)w[(k * 64 + 2 * cp + 1) * 9 + t] & 0xFFFFu;
    g_wpack[i] = lo | (hi << 16);
}

__global__ __launch_bounds__(NTH, 4) void secconv(
    const int* __restrict__ bias, int* __restrict__ out)
{
    __shared__ unsigned sx[4 * PLW];   // 28.8 KB

    const int tid = threadIdx.x;
    const int blk = blockIdx.x;
    const int q   = blk >> 3;
    const int rh  = q & 1;
    const int kg  = (q >> 1) & 15;
    const int n   = (blk & 7) | ((q >> 5) << 3);
    const int k0  = kg * KG;
    const int oh0 = rh * 28;

    // zero all planes once: margins (cols 0,1,58,59 and the one OOB halo
    // row) stay zero forever; interior is overwritten every chunk.
    for (int i = tid; i < 4 * PLW; i += NTH) sx[i] = 0;

    const int orow = tid >> 3;        // 0..27
    const int tc7  = (tid & 7) * 7;   // output col start

    // staging: 812 in-bounds pairs/plane (29 rows x 28 pairs), 4 slots/thread
    const int ihb = rh ? 27 : 0;      // first in-bounds halo row (global)
    const int rb  = rh ? 0 : 1;       // its LDS row
    int goff[4], loff[4];
#pragma unroll
    for (int s = 0; s < 4; ++s) {
        int j  = tid + s * NTH;       // 0..895, valid < 812
        int rr = j / 28, pc = j - rr * 28;
        goff[s] = (ihb + rr) * 56 + 2 * pc;        // x-plane word offset (even)
        loff[s] = (rb + rr) * LDSW + 2 * pc + 2;   // LDS word offset (even)
    }
    const unsigned* xp0 = g_xpack + (long)n * 32 * HW;

    unsigned acc[KG][7];
#pragma unroll
    for (int j = 0; j < KG; ++j) {
        unsigned b = (unsigned)bias[k0 + j];
#pragma unroll
        for (int p = 0; p < 7; ++p) acc[j][p] = b;
    }

    for (int cp0 = 0; cp0 < 32; cp0 += 4) {
        __syncthreads();
#pragma unroll
        for (int pl = 0; pl < 4; ++pl) {
            const unsigned* xp = xp0 + (long)(cp0 + pl) * HW;
#pragma unroll
            for (int s = 0; s < 4; ++s) {
                if (tid + s * NTH < 812) {
                    uint2 v = *(const uint2*)(xp + goff[s]);
                    *(uint2*)(sx + pl * PLW + loff[s]) = v;
                }
            }
        }
        __syncthreads();

#pragma unroll
        for (int pl = 0; pl < 4; ++pl) {
            unsigned win[27];
            const unsigned* tb = sx + pl * PLW + orow * LDSW + tc7 + 1;
#pragma unroll
            for (int dr = 0; dr < 3; ++dr)
#pragma unroll
                for (int u = 0; u < 9; ++u)
                    win[dr * 9 + u] = tb[dr * LDSW + u];

            const unsigned* wp = g_wpack + ((cp0 + pl) * 64 + k0) * 9;
#pragma unroll
            for (int j = 0; j < KG; ++j) {
                unsigned wv[9];
#pragma unroll
                for (int t = 0; t < 9; ++t) wv[t] = wp[j * 9 + t];
#pragma unroll
                for (int t = 0; t < 9; ++t) {
                    const int dr = t / 3, s2 = t - dr * 3;
#pragma unroll
                    for (int p = 0; p < 7; ++p)
                        acc[j][p] = dot2(win[dr * 9 + p + s2], wv[t], acc[j][p]);
                }
            }
        }
    }

    const long ob = ((long)n * 64 + k0) * HW + (long)(oh0 + orow) * 56 + tc7;
#pragma unroll
    for (int j = 0; j < KG; ++j)
#pragma unroll
        for (int p = 0; p < 7; ++p)
            out[ob + (long)j * HW + p] = (int)acc[j][p];
}

extern "C" void kernel_launch(void* const* d_in, const int* in_sizes, int n_in,
                              void* d_out, int out_size, void* d_ws, size_t ws_size,
                              hipStream_t stream)
{
    const int* x    = (const int*)d_in[0];
    const int* w    = (const int*)d_in[1];
    const int* bias = (const int*)d_in[2];
    int* out        = (int*)d_out;

    packx<<<dim3(3136), dim3(256), 0, stream>>>(x);   // 32*32*784 quads
    packw<<<dim3(72),   dim3(256), 0, stream>>>(w);
    secconv<<<dim3(1024), dim3(NTH), 0, stream>>>(bias, out);
}

// Round 5
// 133.572 us; speedup vs baseline: 2.8452x; 1.3423x over previous
//
#include <hip/hip_runtime.h>

// SecConv2d over Z_{2^32} via i8 MFMA (exact).
// x = xl + 256*xh (bytes, stored biased: byte^0x80 -> signed i8 s = byte-128)
// w = b0 + 128*b1 + 16384*b2 (exact limbs, all fit positive i8)
// (sl + 256*sh)*w = (x - 32896)*w  =>  out = sum shifts*P + off[k],
//   off[k] = bias[k] + 32896 * sum_{c,t} w[k][c][t]   (mod 2^32)
// 6 MFMA chains, shifts {0,7,8,14,15,22}; mfma_i32_16x16x64_i8, K = t-major
// (one 3x3 tap = 64 channels = one MFMA). x packed channel-last into padded
// 58x58x64B planes (border byte 0x80 == ring zero) -> every B-frag is one
// contiguous 16B load; weights packed [limb][t][k][c] -> A-frags contiguous.
// Conv kernel: no LDS, no barriers; 27 resident weight frags per wave.

typedef int v4i __attribute__((ext_vector_type(4)));

#define XPW (58 * 58 * 64)   // 215296 bytes per padded image-limb plane

__device__ __align__(16) unsigned char g_xl[32 * XPW];
__device__ __align__(16) unsigned char g_xh[32 * XPW];
__device__ __align__(16) unsigned char g_wb[3 * 9 * 64 * 64];
__device__ unsigned g_off[64];

__global__ __launch_bounds__(256) void padx() {
    int i = blockIdx.x * 256 + threadIdx.x;          // 1682*256 = 430592 quads
    uint4 v = make_uint4(0x80808080u, 0x80808080u, 0x80808080u, 0x80808080u);
    ((uint4*)g_xl)[i] = v;
    ((uint4*)g_xh)[i] = v;
}

__global__ __launch_bounds__(256) void packx(const int* __restrict__ x) {
    int gid = blockIdx.x * 256 + threadIdx.x;        // 32*3136*4
    int q = gid & 3;
    int p = (gid >> 2) % 3136;
    int n = gid / (3136 * 4);
    const int* xp = x + (long)(n * 64 + 16 * q) * 3136 + p;
    unsigned lo[4], hi[4];
#pragma unroll
    for (int wd = 0; wd < 4; ++wd) {
        unsigned l = 0, h = 0;
#pragma unroll
        for (int j = 0; j < 4; ++j) {
            unsigned v = (unsigned)xp[(long)(wd * 4 + j) * 3136];
            l |= (((v      ) & 0xFFu) ^ 0x80u) << (8 * j);
            h |= (((v >>  8) & 0xFFu) ^ 0x80u) << (8 * j);
        }
        lo[wd] = l; hi[wd] = h;
    }
    int hh = p / 56, ww = p - hh * 56;
    long ob = (long)n * XPW + ((hh + 1) * 58 + (ww + 1)) * 64 + 16 * q;
    *(uint4*)(g_xl + ob) = make_uint4(lo[0], lo[1], lo[2], lo[3]);
    *(uint4*)(g_xh + ob) = make_uint4(hi[0], hi[1], hi[2], hi[3]);
}

__global__ __launch_bounds__(256) void packw(const int* __restrict__ w) {
    int i = blockIdx.x * 256 + threadIdx.x;          // 144*256 = 36864
    if (i >= 64 * 64 * 9) return;
    int k = i / 576;
    int r = i - k * 576;
    int c = r / 9;
    int t = r - c * 9;
    unsigned v = (unsigned)w[i];
    g_wb[((0 * 9 + t) * 64 + k) * 64 + c] = (unsigned char)(v & 127u);
    g_wb[((1 * 9 + t) * 64 + k) * 64 + c] = (unsigned char)((v >> 7) & 127u);
    g_wb[((2 * 9 + t) * 64 + k) * 64 + c] = (unsigned char)((v >> 14) & 3u);
}

__global__ __launch_bounds__(64) void offk(const int* __restrict__ w,
                                           const int* __restrict__ bias) {
    int k = blockIdx.x;          // 64 blocks x 64 threads
    int t = threadIdx.x;
    unsigned s = 0;
#pragma unroll
    for (int j = 0; j < 9; ++j) s += (unsigned)w[k * 576 + t * 9 + j];
    for (int o = 32; o; o >>= 1) s += __shfl_down(s, o);
    if (t == 0) g_off[k] = (unsigned)bias[k] + 32896u * s;
}

__global__ __launch_bounds__(256) void secconv(int* __restrict__ out) {
    const int tid  = threadIdx.x;
    const int wid  = tid >> 6;          // wave -> k-tile
    const int lane = tid & 63;
    const int lm   = lane & 15;
    const int lq   = lane >> 4;
    const int k0   = wid * 16;

    const int blk   = blockIdx.x;       // 1568 = 8 xcd * 196
    const int xcd   = blk & 7;
    const int s     = blk >> 3;         // 0..195
    const int n     = xcd + 8 * (s / 49);
    const int strip = s % 49;           // 4 pixel-tiles each

    // resident weight fragments: lane = (kout = k0+lm, c-block = lq*16)
    v4i wf[3][9];
#pragma unroll
    for (int l = 0; l < 3; ++l)
#pragma unroll
        for (int t = 0; t < 9; ++t)
            wf[l][t] = *(const v4i*)(g_wb + (((l * 9 + t) * 64 + (k0 + lm)) * 64 + lq * 16));

    unsigned offv[4];
#pragma unroll
    for (int r = 0; r < 4; ++r) offv[r] = g_off[k0 + lq * 4 + r];

    const unsigned char* xl = g_xl + (long)n * XPW;
    const unsigned char* xh = g_xh + (long)n * XPW;
    const int dt[9] = {0, 64, 128, 3712, 3776, 3840, 7424, 7488, 7552};

#pragma unroll
    for (int tp = 0; tp < 4; ++tp) {
        const int p0  = strip * 64 + tp * 16;
        const int pix = p0 + lm;
        const int h   = pix / 56, w = pix - h * 56;
        const int base = (h * 58 + w) * 64 + lq * 16;

        v4i a0 = {0,0,0,0}, a1 = {0,0,0,0}, a2 = {0,0,0,0},
            a3 = {0,0,0,0}, a4 = {0,0,0,0}, a5 = {0,0,0,0};
#pragma unroll
        for (int t = 0; t < 9; ++t) {
            v4i bl = *(const v4i*)(xl + base + dt[t]);
            v4i bh = *(const v4i*)(xh + base + dt[t]);
            a0 = __builtin_amdgcn_mfma_i32_16x16x64_i8(wf[0][t], bl, a0, 0, 0, 0);
            a1 = __builtin_amdgcn_mfma_i32_16x16x64_i8(wf[0][t], bh, a1, 0, 0, 0);
            a2 = __builtin_amdgcn_mfma_i32_16x16x64_i8(wf[1][t], bl, a2, 0, 0, 0);
            a3 = __builtin_amdgcn_mfma_i32_16x16x64_i8(wf[1][t], bh, a3, 0, 0, 0);
            a4 = __builtin_amdgcn_mfma_i32_16x16x64_i8(wf[2][t], bl, a4, 0, 0, 0);
            a5 = __builtin_amdgcn_mfma_i32_16x16x64_i8(wf[2][t], bh, a5, 0, 0, 0);
        }

        const long ob = ((long)n * 64 + k0 + lq * 4) * 3136 + p0 + lm;
#pragma unroll
        for (int r = 0; r < 4; ++r) {
            unsigned val = (unsigned)a0[r]
                         + ((unsigned)a2[r] << 7)
                         + ((unsigned)a1[r] << 8)
                         + ((unsigned)a4[r] << 14)
                         + ((unsigned)a3[r] << 15)
                         + ((unsigned)a5[r] << 22)
                         + offv[r];
            out[ob + (long)r * 3136] = (int)val;
        }
    }
}

extern "C" void kernel_launch(void* const* d_in, const int* in_sizes, int n_in,
                              void* d_out, int out_size, void* d_ws, size_t ws_size,
                              hipStream_t stream)
{
    const int* x    = (const int*)d_in[0];
    const int* w    = (const int*)d_in[1];
    const int* bias = (const int*)d_in[2];
    int* out        = (int*)d_out;

    padx   <<<dim3(1682), dim3(256), 0, stream>>>();
    packx  <<<dim3(1568), dim3(256), 0, stream>>>(x);
    packw  <<<dim3(144),  dim3(256), 0, stream>>>(w);
    offk   <<<dim3(64),   dim3(64),  0, stream>>>(w, bias);
    secconv<<<dim3(1568), dim3(256), 0, stream>>>(out);
}

// Round 6
// 117.635 us; speedup vs baseline: 3.2307x; 1.1355x over previous
//
#include <hip/hip_runtime.h>

// SecConv2d over Z_{2^32} via i8 MFMA (exact). See R5: x = biased bytes
// (byte^0x80 -> i8, x - 32896 absorbed into per-k offset), w = 3 exact limbs
// b0|b1|b2 (7+7+2 bits), 6 MFMA chains with shifts {0,7,8,14,15,22}.
//
// R6: conv block = 2 output rows x 56 cols, all 64 kout (4 waves x 16).
//  - x packed interleaved: g_xp[n][row58][col58][64B xl | 64B xh]; border
//    cells hold 0x80 (= ring zero), written directly by packx (no padx pass).
//  - secconv stages its 4 padded rows (33.4 KB, LDS col stride 144 for
//    conflict-free b128 reads) ONCE, one barrier, then 7 pixel-tiles of
//    18 ds_read_b128 + 54 MFMA. Weights resident: 27 frags = 108 VGPR,
//    __launch_bounds__(256,3) keeps the allocator at <=170.

typedef int v4i __attribute__((ext_vector_type(4)));

#define XP   (58 * 58 * 128)   // bytes per packed image
#define ROWB (58 * 128)        // 7424 B per packed row
#define LCOL 144               // LDS col stride (128 + 16 pad)
#define LROW (58 * LCOL)       // 8352 B per LDS row

__device__ __align__(16) unsigned char g_xp[32 * XP];      // 13.8 MB
__device__ __align__(16) unsigned char g_wb[3 * 9 * 64 * 64];
__device__ unsigned g_off[64];

__global__ __launch_bounds__(256) void packx(const int* __restrict__ x) {
    int gid = blockIdx.x * 256 + threadIdx.x;   // (n,q,p): 32*4*3364 = 430592
    int p  = gid % 3364;
    int r  = gid / 3364;
    int q  = r & 3;
    int n  = r >> 2;
    int pr = p / 58, pc = p - pr * 58;
    int ih = pr - 1, iw = pc - 1;
    unsigned char* ob = g_xp + (long)n * XP + (long)p * 128 + q * 16;
    if ((unsigned)ih < 56u && (unsigned)iw < 56u) {
        const int* xp = x + ((long)(n * 64 + q * 16)) * 3136 + ih * 56 + iw;
        unsigned lo[4], hi[4];
#pragma unroll
        for (int wd = 0; wd < 4; ++wd) {
            unsigned l = 0, h = 0;
#pragma unroll
            for (int j = 0; j < 4; ++j) {
                unsigned v = (unsigned)xp[(long)(wd * 4 + j) * 3136];
                l |= (((v      ) & 0xFFu) ^ 0x80u) << (8 * j);
                h |= (((v >>  8) & 0xFFu) ^ 0x80u) << (8 * j);
            }
            lo[wd] = l; hi[wd] = h;
        }
        *(uint4*)(ob)      = make_uint4(lo[0], lo[1], lo[2], lo[3]);
        *(uint4*)(ob + 64) = make_uint4(hi[0], hi[1], hi[2], hi[3]);
    } else {
        uint4 v = make_uint4(0x80808080u, 0x80808080u, 0x80808080u, 0x80808080u);
        *(uint4*)(ob)      = v;
        *(uint4*)(ob + 64) = v;
    }
}

__global__ __launch_bounds__(256) void packw(const int* __restrict__ w,
                                             const int* __restrict__ bias) {
    int blk = blockIdx.x;
    if (blk < 144) {
        int i = blk * 256 + threadIdx.x;        // [k][c][t] flat, 36864
        if (i >= 64 * 64 * 9) return;
        int k = i / 576;
        int r = i - k * 576;
        int c = r / 9;
        int t = r - c * 9;
        unsigned v = (unsigned)w[i];
        g_wb[((0 * 9 + t) * 64 + k) * 64 + c] = (unsigned char)(v & 127u);
        g_wb[((1 * 9 + t) * 64 + k) * 64 + c] = (unsigned char)((v >> 7) & 127u);
        g_wb[((2 * 9 + t) * 64 + k) * 64 + c] = (unsigned char)((v >> 14) & 3u);
    } else if (threadIdx.x < 64) {
        int k = threadIdx.x;
        unsigned s = 0;
        for (int j = 0; j < 576; ++j) s += (unsigned)w[k * 576 + j];
        g_off[k] = (unsigned)bias[k] + 32896u * s;
    }
}

__global__ __launch_bounds__(256, 3) void secconv(int* __restrict__ out) {
    __shared__ unsigned char sx[4 * LROW];      // 33408 B

    const int tid  = threadIdx.x;
    const int blk  = blockIdx.x;                // 896 = 8 xcd * 112
    const int q    = blk >> 3;
    const int rp   = q % 28;                    // output row-pair
    const int n    = (blk & 7) + 8 * (q / 28);
    const int wid  = tid >> 6;
    const int lane = tid & 63;
    const int lm   = lane & 15;
    const int lq   = lane >> 4;
    const int k0   = wid * 16;

    // ---- stage 4 padded global rows -> LDS (pad col stride to 144) ----
    const unsigned char* gp = g_xp + (long)n * XP + (long)(2 * rp) * ROWB;
#pragma unroll
    for (int s = 0; s < 8; ++s) {
        int i = tid + s * 256;                  // 16B chunks, 1856 total
        if (i < 1856) {
            uint4 v = *(const uint4*)(gp + 16 * i);
            int grow = i / 464;
            int j    = i - grow * 464;
            int gcol = j >> 3, sub = j & 7;
            *(uint4*)(sx + grow * LROW + gcol * LCOL + sub * 16) = v;
        }
    }

    // ---- resident weight fragments (overlap with staging latency) ----
    v4i wf0[9], wf1[9], wf2[9];
#pragma unroll
    for (int t = 0; t < 9; ++t) {
        const unsigned char* wb = g_wb + (((t) * 64 + (k0 + lm)) * 64 + lq * 16);
        wf0[t] = *(const v4i*)(wb);
        wf1[t] = *(const v4i*)(wb + 9 * 64 * 64);
        wf2[t] = *(const v4i*)(wb + 18 * 64 * 64);
    }
    unsigned offv[4];
#pragma unroll
    for (int r = 0; r < 4; ++r) offv[r] = g_off[k0 + lq * 4 + r];

    __syncthreads();

    const int r8 = lm >> 3, c8 = lm & 7;        // pixel tile: 2 rows x 8 cols
    const unsigned char* lbase = sx + r8 * LROW + c8 * LCOL + lq * 16;

    for (int t = 0; t < 7; ++t) {               // 7 col-groups of 8
        const unsigned char* tb = lbase + t * 8 * LCOL;
        v4i a0 = {0,0,0,0}, a1 = {0,0,0,0}, a2 = {0,0,0,0},
            a3 = {0,0,0,0}, a4 = {0,0,0,0}, a5 = {0,0,0,0};
#pragma unroll
        for (int tap = 0; tap < 9; ++tap) {
            const int dr = tap / 3, dc = tap - (tap / 3) * 3;
            const unsigned char* pp = tb + dr * LROW + dc * LCOL;
            v4i bl = *(const v4i*)(pp);
            v4i bh = *(const v4i*)(pp + 64);
            a0 = __builtin_amdgcn_mfma_i32_16x16x64_i8(wf0[tap], bl, a0, 0, 0, 0);
            a1 = __builtin_amdgcn_mfma_i32_16x16x64_i8(wf0[tap], bh, a1, 0, 0, 0);
            a2 = __builtin_amdgcn_mfma_i32_16x16x64_i8(wf1[tap], bl, a2, 0, 0, 0);
            a3 = __builtin_amdgcn_mfma_i32_16x16x64_i8(wf1[tap], bh, a3, 0, 0, 0);
            a4 = __builtin_amdgcn_mfma_i32_16x16x64_i8(wf2[tap], bl, a4, 0, 0, 0);
            a5 = __builtin_amdgcn_mfma_i32_16x16x64_i8(wf2[tap], bh, a5, 0, 0, 0);
        }

        const long ob = ((long)n * 64 + k0 + lq * 4) * 3136
                      + (long)(2 * rp + r8) * 56 + t * 8 + c8;
#pragma unroll
        for (int r = 0; r < 4; ++r) {
            unsigned val = (unsigned)a0[r]
                         + ((unsigned)a2[r] << 7)
                         + ((unsigned)a1[r] << 8)
                         + ((unsigned)a4[r] << 14)
                         + ((unsigned)a3[r] << 15)
                         + ((unsigned)a5[r] << 22)
                         + offv[r];
            out[ob + (long)r * 3136] = (int)val;
        }
    }
}

extern "C" void kernel_launch(void* const* d_in, const int* in_sizes, int n_in,
                              void* d_out, int out_size, void* d_ws, size_t ws_size,
                              hipStream_t stream)
{
    const int* x    = (const int*)d_in[0];
    const int* w    = (const int*)d_in[1];
    const int* bias = (const int*)d_in[2];
    int* out        = (int*)d_out;

    packx  <<<dim3(1682), dim3(256), 0, stream>>>(x);
    packw  <<<dim3(145),  dim3(256), 0, stream>>>(w, bias);
    secconv<<<dim3(896),  dim3(256), 0, stream>>>(out);
}